// Round 1
// baseline (276.578 us; speedup 1.0000x reference)
//
#include <hip/hip_runtime.h>
#include <stdint.h>

#define Bb 8
#define Dd 256
#define Ll 4096
#define Kk 4096
#define Nn (Bb * Ll)          // 32768 rows
#define NCB (Kk / 128)        // 32 column blocks
#define OUT0 (Bb * Dd * Ll)   // 8388608

typedef short short8 __attribute__((ext_vector_type(8)));
typedef float floatx4 __attribute__((ext_vector_type(4)));

__device__ __forceinline__ unsigned short f32_to_bf16(float f) {
    union { float f; uint32_t u; } v; v.f = f;
    return (unsigned short)((v.u + 0x7FFFu + ((v.u >> 16) & 1u)) >> 16);
}

__device__ __forceinline__ void async_load16(const void* g, void* l) {
    __builtin_amdgcn_global_load_lds((const __attribute__((address_space(1))) void*)g,
                                     (__attribute__((address_space(3))) void*)l, 16, 0, 0);
}

// ---------------------------------------------------------------- kernel 1
// normalize codebook rows, cast to bf16: wn[k][d] = w[k][d]/max(||w_k||,eps)
__global__ void k_norm_w(const float* __restrict__ w, unsigned short* __restrict__ wn) {
    int row  = blockIdx.x * 4 + (threadIdx.x >> 6);
    int lane = threadIdx.x & 63;
    float4 v = ((const float4*)(w + (size_t)row * Dd))[lane];
    float ss = v.x * v.x + v.y * v.y + v.z * v.z + v.w * v.w;
#pragma unroll
    for (int m = 1; m < 64; m <<= 1) ss += __shfl_xor(ss, m, 64);
    float s = 1.0f / fmaxf(sqrtf(ss), 1e-12f);
    ushort4 o;
    o.x = f32_to_bf16(v.x * s); o.y = f32_to_bf16(v.y * s);
    o.z = f32_to_bf16(v.z * s); o.w = f32_to_bf16(v.w * s);
    ((ushort4*)(wn + (size_t)row * Dd))[lane] = o;
}

// ---------------------------------------------------------------- kernel 2
// inputs [B,D,L] fp32  ->  A [B*L, D] bf16 (row-major)
__global__ void k_transpose(const float* __restrict__ x, unsigned short* __restrict__ A) {
    __shared__ unsigned short tile[64][66];
    int bid = blockIdx.x;
    int lb = bid & 63;          // L/64
    int db = (bid >> 6) & 3;    // D/64
    int b  = bid >> 8;
    int tx = threadIdx.x & 63;
    int ty = threadIdx.x >> 6;
    const float* src = x + ((size_t)b * Dd + db * 64) * Ll + lb * 64;
#pragma unroll
    for (int dy = ty; dy < 64; dy += 4)
        tile[dy][tx] = f32_to_bf16(src[(size_t)dy * Ll + tx]);
    __syncthreads();
    unsigned short* dst = A + ((size_t)(b * Ll + lb * 64)) * Dd + db * 64;
#pragma unroll
    for (int ly = ty; ly < 64; ly += 4)
        dst[(size_t)ly * Dd + tx] = tile[tx][ly];
}

// ---------------------------------------------------------------- kernel 3
// C = A[N,D] x Wn[K,D]^T, argmax over the 128 cols of this block,
// write per-(row, colblock) partial (val, idx).
// BM=BN=128, BK=64 (2 MFMA k-steps / frag / iter), 256 thr = 4 waves (2x2 of 64x64)
__global__ __launch_bounds__(256) void k_gemm_argmax(
        const unsigned short* __restrict__ A, const unsigned short* __restrict__ Wn,
        float* __restrict__ pv, int* __restrict__ pi) {
    __shared__ __align__(16) unsigned short As[128 * 64];  // [row][64k], 16B-chunk-swizzled
    __shared__ __align__(16) unsigned short Bs[128 * 64];
    __shared__ float red_v[128][2];
    __shared__ int   red_i[128][2];

    int blk = blockIdx.x;
    int bn = blk & (NCB - 1);
    int bm = blk >> 5;
    int tid = threadIdx.x;
    int lane = tid & 63;
    int w = tid >> 6;
    int wm = w >> 1, wn = w & 1;
    int l15 = lane & 15, l4 = lane >> 4;

    const unsigned short* Abase = A  + (size_t)bm * 128 * Dd;
    const unsigned short* Bbase = Wn + (size_t)bn * 128 * Dd;

    // staging: tile = 128 rows x 128B = 1024 16B-chunks; 4 issues/thread.
    // LDS chunk q = j*256+tid holds global chunk (r=q>>3, qg=((q&7)-(r>>1))&7)
    const char* gA[4]; const char* gB[4]; char* lA[4]; char* lB[4];
#pragma unroll
    for (int j = 0; j < 4; ++j) {
        int q = j * 256 + tid;
        int r = q >> 3;
        int qg = ((q & 7) - (r >> 1)) & 7;
        gA[j] = (const char*)Abase + (size_t)r * (Dd * 2) + qg * 16;
        gB[j] = (const char*)Bbase + (size_t)r * (Dd * 2) + qg * 16;
        lA[j] = (char*)As + q * 16;
        lB[j] = (char*)Bs + q * 16;
    }

    // fragment LDS read pointers (fixed across K iters): chunk c' = (qc + (m>>1))&7
    const short8* aptr[4][2]; const short8* bptr[4][2];
#pragma unroll
    for (int f = 0; f < 4; ++f)
#pragma unroll
        for (int s = 0; s < 2; ++s) {
            int ma = wm * 64 + f * 16 + l15;
            int ca = ((s * 4 + l4) + (ma >> 1)) & 7;
            aptr[f][s] = (const short8*)((const char*)As + ma * 128 + ca * 16);
            int mb = wn * 64 + f * 16 + l15;
            int cb = ((s * 4 + l4) + (mb >> 1)) & 7;
            bptr[f][s] = (const short8*)((const char*)Bs + mb * 128 + cb * 16);
        }

    floatx4 acc[4][4] = {};
#pragma unroll
    for (int kk = 0; kk < 4; ++kk) {            // D=256 / BK=64
        __syncthreads();
#pragma unroll
        for (int j = 0; j < 4; ++j) {
            async_load16(gA[j] + kk * 128, lA[j]);
            async_load16(gB[j] + kk * 128, lB[j]);
        }
        __syncthreads();                        // barrier drains vmcnt
        short8 af[4][2], bf[4][2];
#pragma unroll
        for (int f = 0; f < 4; ++f)
#pragma unroll
            for (int s = 0; s < 2; ++s) { af[f][s] = *aptr[f][s]; bf[f][s] = *bptr[f][s]; }
#pragma unroll
        for (int s = 0; s < 2; ++s)
#pragma unroll
            for (int fm = 0; fm < 4; ++fm)
#pragma unroll
                for (int fn = 0; fn < 4; ++fn)
                    acc[fm][fn] = __builtin_amdgcn_mfma_f32_16x16x32_bf16(
                        af[fm][s], bf[fn][s], acc[fm][fn], 0, 0, 0);
    }

    // epilogue: per-row argmax over this block's 128 cols
    int colbase = bn * 128 + wn * 64 + l15;
#pragma unroll
    for (int fm = 0; fm < 4; ++fm)
#pragma unroll
        for (int r = 0; r < 4; ++r) {
            float v = acc[fm][0][r]; int ix = colbase;
#pragma unroll
            for (int fn = 1; fn < 4; ++fn) {
                float vv = acc[fm][fn][r];
                if (vv > v) { v = vv; ix = colbase + fn * 16; }
            }
#pragma unroll
            for (int md = 1; md <= 8; md <<= 1) {     // reduce across 16 lanes of quad-group
                float ov = __shfl_xor(v, md, 64);
                int   oi = __shfl_xor(ix, md, 64);
                if (ov > v || (ov == v && oi < ix)) { v = ov; ix = oi; }
            }
            if (l15 == 0) {
                int row = wm * 64 + fm * 16 + l4 * 4 + r;
                red_v[row][wn] = v; red_i[row][wn] = ix;
            }
        }
    __syncthreads();
    if (tid < 128) {
        float v0 = red_v[tid][0], v1 = red_v[tid][1];
        int   i0 = red_i[tid][0], i1 = red_i[tid][1];
        float v = v0; int ix = i0;
        if (v1 > v0) { v = v1; ix = i1; }   // tie keeps smaller idx (wn=0)
        size_t n = (size_t)bm * 128 + tid;
        pv[(size_t)bn * Nn + n] = v;
        pi[(size_t)bn * Nn + n] = ix;
    }
}

// ---------------------------------------------------------------- kernel 4
// final argmax across 32 col-blocks + histogram
__global__ void k_reduce(const float* __restrict__ pv, const int* __restrict__ pi,
                         int* __restrict__ idx, int* __restrict__ counts) {
    int n = blockIdx.x * 256 + threadIdx.x;
    float v = pv[n]; int ix = pi[n];
#pragma unroll
    for (int cb = 1; cb < NCB; ++cb) {
        float vv = pv[(size_t)cb * Nn + n];
        int   ii = pi[(size_t)cb * Nn + n];
        if (vv > v) { v = vv; ix = ii; }    // strict >: first-max kept (cb ascending)
    }
    idx[n] = ix;
    atomicAdd(&counts[ix], 1);
}

// ---------------------------------------------------------------- kernel 5
// out0[b,d,l] = w[idx[b*L+l]][d]; accumulate sum((q-x)^2)
__global__ void k_gather(const float* __restrict__ w, const float* __restrict__ x,
                         const int* __restrict__ idx, float* __restrict__ out,
                         float* __restrict__ lossacc) {
    __shared__ float wt[32][257];
    int bid = blockIdx.x;
    int b  = bid >> 7;               // L/32 = 128 tiles
    int l0 = (bid & 127) * 32;
    int tid = threadIdx.x;
    int tx = tid & 31, tg = tid >> 5;        // 8 groups
    __shared__ int kidx[32];
    if (tid < 32) kidx[tid] = idx[b * Ll + l0 + tid];
    __syncthreads();
#pragma unroll
    for (int r = tg; r < 32; r += 8) {
        int k = kidx[r];
#pragma unroll
        for (int j = 0; j < 8; ++j)
            wt[r][tx + 32 * j] = w[(size_t)k * Dd + tx + 32 * j];
    }
    __syncthreads();
    float ls = 0.f;
    const float* xb = x + (size_t)b * Dd * Ll + l0;
    float* ob = out + (size_t)b * Dd * Ll + l0;
    for (int d = tg; d < Dd; d += 8) {
        float q  = wt[tx][d];
        float xv = xb[(size_t)d * Ll + tx];
        float df = q - xv;
        ls += df * df;
        ob[(size_t)d * Ll + tx] = q;
    }
#pragma unroll
    for (int m = 1; m < 64; m <<= 1) ls += __shfl_xor(ls, m, 64);
    __shared__ float wsum[4];
    if ((tid & 63) == 0) wsum[tid >> 6] = ls;
    __syncthreads();
    if (tid == 0) atomicAdd(lossacc, wsum[0] + wsum[1] + wsum[2] + wsum[3]);
}

// ---------------------------------------------------------------- kernel 6
__global__ void k_final(const int* __restrict__ counts, const float* __restrict__ lossacc,
                        float* __restrict__ out) {
    int tid = threadIdx.x;
    float s = 0.f;
    for (int i = tid; i < Kk; i += 256) {
        float p = (float)counts[i] * (1.0f / Nn);
        s += p * logf(p + 1e-10f);
    }
#pragma unroll
    for (int m = 1; m < 64; m <<= 1) s += __shfl_xor(s, m, 64);
    __shared__ float ws_[4];
    if ((tid & 63) == 0) ws_[tid >> 6] = s;
    __syncthreads();
    if (tid == 0) {
        out[OUT0]     = lossacc[0] * 1.25f / (float)OUT0;   // q_latent + 0.25*e_latent
        out[OUT0 + 1] = expf(-(ws_[0] + ws_[1] + ws_[2] + ws_[3]));
    }
}

// ---------------------------------------------------------------- launch
extern "C" void kernel_launch(void* const* d_in, const int* in_sizes, int n_in,
                              void* d_out, int out_size, void* d_ws, size_t ws_size,
                              hipStream_t stream) {
    const float* x = (const float*)d_in[0];   // [B, D, L]
    const float* w = (const float*)d_in[1];   // [K, D]
    float* out = (float*)d_out;
    char* ws = (char*)d_ws;

    unsigned short* wn = (unsigned short*)ws;                         //  2 MB
    unsigned short* A  = (unsigned short*)(ws + (2u  << 20));         // 16 MB
    float* pv          = (float*)(ws + (18u << 20));                  //  4 MB
    int*   pi          = (int*)  (ws + (22u << 20));                  //  4 MB
    int*   idx         = (int*)  (ws + (26u << 20));                  // 128 KB
    int*   counts      = (int*)  (ws + (26u << 20) + (128u << 10));   // 16 KB
    float* lossacc     = (float*)(ws + (26u << 20) + (144u << 10));   // 4 B

    hipMemsetAsync(counts, 0, (16u << 10) + 4, stream);   // counts + lossacc

    k_norm_w   <<<Kk / 4,            256, 0, stream>>>(w, wn);
    k_transpose<<<Bb * 4 * 64,       256, 0, stream>>>(x, A);
    k_gemm_argmax<<<(Nn / 128) * NCB, 256, 0, stream>>>(A, wn, pv, pi);
    k_reduce   <<<Nn / 256,          256, 0, stream>>>(pv, pi, idx, counts);
    k_gather   <<<Bb * (Ll / 32),    256, 0, stream>>>(w, x, idx, out, lossacc);
    k_final    <<<1,                 256, 0, stream>>>(counts, lossacc, out);
}

// Round 2
// 192.708 us; speedup vs baseline: 1.4352x; 1.4352x over previous
//
#include <hip/hip_runtime.h>
#include <stdint.h>

#define Bb 8
#define Dd 256
#define Ll 4096
#define Kk 4096
#define Nn (Bb * Ll)          // 32768 rows
#define OUT0 (Bb * Dd * Ll)   // 8388608

typedef short short8 __attribute__((ext_vector_type(8)));
typedef float floatx4 __attribute__((ext_vector_type(4)));

__device__ __forceinline__ unsigned short f32_to_bf16(float f) {
    union { float f; uint32_t u; } v; v.f = f;
    return (unsigned short)((v.u + 0x7FFFu + ((v.u >> 16) & 1u)) >> 16);
}

__device__ __forceinline__ void async_load16(const void* g, void* l) {
    __builtin_amdgcn_global_load_lds((const __attribute__((address_space(1))) void*)g,
                                     (__attribute__((address_space(3))) void*)l, 16, 0, 0);
}

// ---------------------------------------------------------------- kernel 1
// fused: [blocks 0..1023] codebook normalize->bf16 (+block 0 zeroes counts)
//        [blocks 1024..2047] transpose x [B,D,L]f32 -> A [B*L,D]bf16
__global__ void k_prep(const float* __restrict__ x, const float* __restrict__ w,
                       unsigned short* __restrict__ A, unsigned short* __restrict__ wn,
                       int* __restrict__ counts) {
    __shared__ ushort2 tile[64][65];   // transpose tile (d-pairs), +1 pad
    int blk = blockIdx.x;
    int tid = threadIdx.x;
    if (blk < 1024) {
        if (blk == 0)
            for (int i = tid; i < Kk + 1; i += 256) counts[i] = 0;  // counts + lossacc
        int row  = blk * 4 + (tid >> 6);
        int lane = tid & 63;
        float4 v = ((const float4*)(w + (size_t)row * Dd))[lane];
        float ss = v.x*v.x + v.y*v.y + v.z*v.z + v.w*v.w;
#pragma unroll
        for (int m = 1; m < 64; m <<= 1) ss += __shfl_xor(ss, m, 64);
        float s = 1.0f / fmaxf(sqrtf(ss), 1e-12f);
        ushort4 o;
        o.x = f32_to_bf16(v.x*s); o.y = f32_to_bf16(v.y*s);
        o.z = f32_to_bf16(v.z*s); o.w = f32_to_bf16(v.w*s);
        ((ushort4*)(wn + (size_t)row * Dd))[lane] = o;
    } else {
        int t  = blk - 1024;
        int lb = t & 63, db = (t >> 6) & 1, b = t >> 7;
        int tx = tid & 63, ty = tid >> 6;
        const float* src = x + ((size_t)b * Dd + db * 128) * Ll + lb * 64;
#pragma unroll
        for (int i = 0; i < 16; ++i) {
            int dp = ty + 4 * i;                     // d-pair index 0..63
            float a0 = src[(size_t)(2*dp)   * Ll + tx];
            float a1 = src[(size_t)(2*dp+1) * Ll + tx];
            ushort2 u; u.x = f32_to_bf16(a0); u.y = f32_to_bf16(a1);
            tile[tx][dp] = u;
        }
        __syncthreads();
        unsigned short* dst = A + (size_t)(b * Ll + lb * 64) * Dd + db * 128;
#pragma unroll
        for (int i = 0; i < 16; ++i) {
            int l = ty + 4 * i;
            ((ushort2*)(dst + (size_t)l * Dd))[tx] = tile[l][tx];
        }
    }
}

// ---------------------------------------------------------------- kernel 2
// argmax_k <A_n, Wn_k>: A-frags resident in registers (full K=256),
// B double-buffered 64-row col-blocks, register running argmax.
// grid = 256 row-blocks x 2 col-groups; 4 waves = 2x2 (wm rows, wn cols).
__global__ __launch_bounds__(256, 2) void k_gemm_argmax(
        const unsigned short* __restrict__ A, const unsigned short* __restrict__ Wn,
        float* __restrict__ pv, int* __restrict__ pi) {
    __shared__ __align__(16) unsigned short Bs[2][64 * 256];   // 2 x 32KB
    __shared__ float red_v[128][2];
    __shared__ int   red_i[128][2];

    int blk = blockIdx.x;
    int cg  = blk & 1;          // col-group: cols cg*2048 .. +2048
    int bm  = blk >> 1;         // row-block: rows bm*128 .. +128
    int tid = threadIdx.x, lane = tid & 63, w = tid >> 6;
    int wm = w >> 1, wn = w & 1;
    int l15 = lane & 15, l4 = lane >> 4;

    // ---- A fragments in registers: row = bm*128+wm*64+fm*16+l15, k = kk*32+l4*8
    const unsigned short* Arow = A + (size_t)(bm * 128 + wm * 64 + l15) * Dd + l4 * 8;
    short8 af[4][8];
#pragma unroll
    for (int fm = 0; fm < 4; ++fm)
#pragma unroll
        for (int kk = 0; kk < 8; ++kk)
            af[fm][kk] = *(const short8*)(Arow + fm * 16 * Dd + kk * 32);

    // ---- staging map: LDS slot q=w*512+j*64+lane holds global chunk
    // (r=q>>5, c=((q&31)-r)&31); global side = full 512B rows, coalesced.
    int goff[8], loff[8];
#pragma unroll
    for (int j = 0; j < 8; ++j) {
        int q = w * 512 + j * 64 + lane;
        int r = q >> 5, c = ((q & 31) - r) & 31;
        goff[j] = r * 512 + c * 16;
        loff[j] = q * 16;
    }
    const char* Wg = (const char*)Wn + (size_t)cg * 2048 * 512;  // 512 B/row

    int r0 = wn * 32 + l15;     // fn=0 B-row; fn=1 adds 16

    float rv[4][4]; int ri[4][4];
#pragma unroll
    for (int fm = 0; fm < 4; ++fm)
#pragma unroll
        for (int r = 0; r < 4; ++r) { rv[fm][r] = -3.0e38f; ri[fm][r] = 0; }

    // prologue: stage col-block 0 into buf 0
#pragma unroll
    for (int j = 0; j < 8; ++j)
        async_load16(Wg + goff[j], (char*)Bs + loff[j]);
    __syncthreads();

    for (int cb = 0; cb < 32; ++cb) {
        int cur = cb & 1;
        if (cb < 31) {          // prefetch next col-block into other buffer
            const char* g = Wg + (size_t)(cb + 1) * 32768;
            char* l = (char*)Bs + (cur ^ 1) * 32768;
#pragma unroll
            for (int j = 0; j < 8; ++j)
                async_load16(g + goff[j], l + loff[j]);
        }
        const char* bbuf = (const char*)Bs + cur * 32768;
        floatx4 acc[4][2] = {};
#pragma unroll
        for (int kk = 0; kk < 8; ++kk) {
            int c = kk * 4 + l4;
            short8 b0 = *(const short8*)(bbuf + r0 * 512 + (((c + r0) & 31) << 4));
            short8 b1 = *(const short8*)(bbuf + (r0 + 16) * 512 + (((c + r0 + 16) & 31) << 4));
#pragma unroll
            for (int fm = 0; fm < 4; ++fm) {
                acc[fm][0] = __builtin_amdgcn_mfma_f32_16x16x32_bf16(af[fm][kk], b0, acc[fm][0], 0, 0, 0);
                acc[fm][1] = __builtin_amdgcn_mfma_f32_16x16x32_bf16(af[fm][kk], b1, acc[fm][1], 0, 0, 0);
            }
        }
        // running argmax (ascending cb/fn + strict '>' keeps lowest index on ties)
        int cbase = cb * 64 + wn * 32 + l15;
#pragma unroll
        for (int fm = 0; fm < 4; ++fm)
#pragma unroll
            for (int r = 0; r < 4; ++r)
#pragma unroll
                for (int fn = 0; fn < 2; ++fn) {
                    float v = acc[fm][fn][r];
                    int ix = cbase + fn * 16;
                    if (v > rv[fm][r]) { rv[fm][r] = v; ri[fm][r] = ix; }
                }
        __syncthreads();        // guards buf reuse + drains prefetch DMA
    }

    // epilogue: reduce across the 16 column-lanes, then across wn halves
#pragma unroll
    for (int fm = 0; fm < 4; ++fm)
#pragma unroll
        for (int r = 0; r < 4; ++r) {
            float v = rv[fm][r]; int ix = ri[fm][r];
#pragma unroll
            for (int md = 1; md <= 8; md <<= 1) {
                float ov = __shfl_xor(v, md, 64);
                int   oi = __shfl_xor(ix, md, 64);
                if (ov > v || (ov == v && oi < ix)) { v = ov; ix = oi; }
            }
            if (l15 == 0) {
                int row = wm * 64 + fm * 16 + l4 * 4 + r;
                red_v[row][wn] = v; red_i[row][wn] = ix;
            }
        }
    __syncthreads();
    if (tid < 128) {
        float v0 = red_v[tid][0], v1 = red_v[tid][1];
        int   i0 = red_i[tid][0], i1 = red_i[tid][1];
        float v = v0; int ix = i0;
        if (v1 > v0 || (v1 == v0 && i1 < i0)) { v = v1; ix = i1; }
        size_t n = (size_t)bm * 128 + tid;
        pv[(size_t)cg * Nn + n] = v;
        pi[(size_t)cg * Nn + n] = cg * 2048 + ix;
    }
}

// ---------------------------------------------------------------- kernel 3
// final argmax over 2 col-groups + histogram + gather + loss accumulation
__global__ void k_gather(const float* __restrict__ w, const float* __restrict__ x,
                         const float* __restrict__ pv, const int* __restrict__ pi,
                         float* __restrict__ out, float* __restrict__ lossacc,
                         int* __restrict__ counts) {
    __shared__ float wt[32][257];
    __shared__ int kidx[32];
    int bid = blockIdx.x;
    int b  = bid >> 7;
    int l0 = (bid & 127) * 32;
    int tid = threadIdx.x;
    int tx = tid & 31, tg = tid >> 5;
    if (tid < 32) {
        int n = b * Ll + l0 + tid;
        float v0 = pv[n], v1 = pv[Nn + n];
        int   i0 = pi[n], i1 = pi[Nn + n];
        int ix = (v1 > v0 || (v1 == v0 && i1 < i0)) ? i1 : i0;
        kidx[tid] = ix;
        atomicAdd(&counts[ix], 1);
    }
    __syncthreads();
#pragma unroll
    for (int r = tg; r < 32; r += 8) {
        int k = kidx[r];
#pragma unroll
        for (int j = 0; j < 8; ++j)
            wt[r][tx + 32 * j] = w[(size_t)k * Dd + tx + 32 * j];
    }
    __syncthreads();
    float ls = 0.f;
    const float* xb = x + (size_t)b * Dd * Ll + l0;
    float* ob = out + (size_t)b * Dd * Ll + l0;
    for (int d = tg; d < Dd; d += 8) {
        float q  = wt[tx][d];
        float xv = xb[(size_t)d * Ll + tx];
        float df = q - xv;
        ls += df * df;
        ob[(size_t)d * Ll + tx] = q;
    }
#pragma unroll
    for (int m = 1; m < 64; m <<= 1) ls += __shfl_xor(ls, m, 64);
    __shared__ float wsum[4];
    if ((tid & 63) == 0) wsum[tid >> 6] = ls;
    __syncthreads();
    if (tid == 0) atomicAdd(lossacc, wsum[0] + wsum[1] + wsum[2] + wsum[3]);
}

// ---------------------------------------------------------------- kernel 4
__global__ void k_final(const int* __restrict__ counts, const float* __restrict__ lossacc,
                        float* __restrict__ out) {
    int tid = threadIdx.x;
    float s = 0.f;
    for (int i = tid; i < Kk; i += 256) {
        float p = (float)counts[i] * (1.0f / Nn);
        s += p * logf(p + 1e-10f);
    }
#pragma unroll
    for (int m = 1; m < 64; m <<= 1) s += __shfl_xor(s, m, 64);
    __shared__ float ws_[4];
    if ((tid & 63) == 0) ws_[tid >> 6] = s;
    __syncthreads();
    if (tid == 0) {
        out[OUT0]     = lossacc[0] * 1.25f / (float)OUT0;   // q_latent + 0.25*e_latent
        out[OUT0 + 1] = expf(-(ws_[0] + ws_[1] + ws_[2] + ws_[3]));
    }
}

// ---------------------------------------------------------------- launch
extern "C" void kernel_launch(void* const* d_in, const int* in_sizes, int n_in,
                              void* d_out, int out_size, void* d_ws, size_t ws_size,
                              hipStream_t stream) {
    const float* x = (const float*)d_in[0];   // [B, D, L]
    const float* w = (const float*)d_in[1];   // [K, D]
    float* out = (float*)d_out;
    char* ws = (char*)d_ws;

    unsigned short* wn = (unsigned short*)ws;                      //  2 MB
    unsigned short* A  = (unsigned short*)(ws + (2u  << 20));      // 16 MB
    float* pv          = (float*)(ws + (18u << 20));               // 256 KB
    int*   pi          = (int*)  (ws + (18u << 20) + (256u << 10));// 256 KB
    int*   counts      = (int*)  (ws + (19u << 20));               // 16 KB + 4
    float* lossacc     = (float*)(counts + Kk);

    k_prep       <<<2048, 256, 0, stream>>>(x, w, A, wn, counts);
    k_gemm_argmax<<<512,  256, 0, stream>>>(A, wn, pv, pi);
    k_gather     <<<Bb * (Ll / 32), 256, 0, stream>>>(w, x, pv, pi, out, lossacc, counts);
    k_final      <<<1,    256, 0, stream>>>(counts, lossacc, out);
}